// Round 12
// baseline (826.101 us; speedup 1.0000x reference)
//
#include <hip/hip_runtime.h>
#include <math.h>

typedef __bf16 bf16_t;
typedef __bf16 bf16x8 __attribute__((ext_vector_type(8)));
typedef float  f32x4  __attribute__((ext_vector_type(4)));

__device__ __forceinline__ void gl2lds16(const void* g, void* l) {
  __builtin_amdgcn_global_load_lds((__attribute__((address_space(1))) void*)g,
                                   (__attribute__((address_space(3))) void*)l,
                                   16, 0, 0);
}

#define MFMA16(a, b, c) __builtin_amdgcn_mfma_f32_16x16x32_bf16(a, b, c, 0, 0, 0)

// ---------------------------------------------------------------------------
// QKV GEMM, 256x256 tile, BK=64, 8 waves (2M x 4N), 2 LDS buffers (128 KiB).
// Rationale: the 128' structure is at ~93% of its LDS-BW ceiling
// (0.095 B/MAC); 256'/8-wave is 0.053 B/MAC -> ~1.7x headroom.
// Schedule (one barrier per tile, no pins -- R4-R8 poisons removed):
//   t: vmcnt(0)  [tile-t loads, issued one full tile-body (~2400cy) earlier]
//      s_barrier [all waves' loads landed; all done reading buf s^1]
//      stage(t+1) -> buf s^1   [safe: its readers passed the barrier]
//      24 ds_read_b128 + 64 MFMA on buf s   [compiler-scheduled]
// T2 swizzle identical to the R9/R11-verified 128B-row pattern (0 conflicts).
// Epilogue: seg = n0>>11: 0->q=sigmoid, 1->k=sigmoid(-v)+g=logsigmoid, 2->v.
// ---------------------------------------------------------------------------
__global__ __launch_bounds__(512, 1)
void gemm256s(const bf16_t* __restrict__ A, const bf16_t* __restrict__ Bw,
              bf16_t* __restrict__ oq, bf16_t* __restrict__ okk,
              bf16_t* __restrict__ ov, float* __restrict__ og,
              int M, int N, int K)
{
  extern __shared__ __align__(16) char smem[];
  const int tt = threadIdx.x;
  const int wave = tt >> 6, lane = tt & 63;
  const int wm = wave >> 2, wn = wave & 3;
  const int nbn = N >> 8;
  const int m0 = (int)(blockIdx.x / nbn) << 8;
  const int n0 = (int)(blockIdx.x % nbn) << 8;
  const int l15 = lane & 15, lq = lane >> 4;

  // read-side swizzled column byte offsets within a 128B row (k-halves 0/1)
  const int tk0 = (lq * 16) ^ ((lane & 7) << 4);
  const int tk1 = (64 + lq * 16) ^ ((lane & 7) << 4);

  // staging: thread covers LDS bytes tt*16 + i*8192 of each 32KB panel
  // -> row = (tt>>3) + i*64, slot = tt&7; pre-swizzled global granule
  const int srow = tt >> 3;
  const int sg = (tt & 7) ^ (srow & 7);
  const bf16_t* pA = A  + (size_t)(m0 + srow) * K + sg * 8;
  const bf16_t* pB = Bw + (size_t)(n0 + srow) * K + sg * 8;
  const size_t rstep = (size_t)64 * K;

  f32x4 acc[8][4] = {};
  const int T = K >> 6;

  auto stage = [&](int t, int sl) {
    const int kt = t << 6;
    char* base = smem + sl * 65536 + tt * 16;
    #pragma unroll
    for (int i = 0; i < 4; i++) {
      gl2lds16(pA + i * rstep + kt, base + i * 8192);
      gl2lds16(pB + i * rstep + kt, base + 32768 + i * 8192);
    }
  };

  stage(0, 0);

  for (int t = 0; t < T; t++) {
    const int s = t & 1;
    asm volatile("s_waitcnt vmcnt(0)" ::: "memory");  // tile-t loads landed
    __builtin_amdgcn_s_barrier();                     // all waves: loads + prev reads done
    if (t + 1 < T) stage(t + 1, s ^ 1);               // buf s^1 free (readers passed barrier)

    const char* as = smem + s * 65536;
    const char* bs = as + 32768;

    bf16x8 bfr[4][2];
    #pragma unroll
    for (int nf = 0; nf < 4; nf++) {
      const char* rp = bs + (wn * 64 + nf * 16 + l15) * 128;
      bfr[nf][0] = *(const bf16x8*)(rp + tk0);
      bfr[nf][1] = *(const bf16x8*)(rp + tk1);
    }
    #pragma unroll
    for (int h = 0; h < 2; h++) {
      bf16x8 af[4][2];
      #pragma unroll
      for (int mf = 0; mf < 4; mf++) {
        const char* rp = as + (wm * 128 + (h * 4 + mf) * 16 + l15) * 128;
        af[mf][0] = *(const bf16x8*)(rp + tk0);
        af[mf][1] = *(const bf16x8*)(rp + tk1);
      }
      #pragma unroll
      for (int mf = 0; mf < 4; mf++)
        #pragma unroll
        for (int nf = 0; nf < 4; nf++) {
          acc[h * 4 + mf][nf] = MFMA16(af[mf][0], bfr[nf][0], acc[h * 4 + mf][nf]);
          acc[h * 4 + mf][nf] = MFMA16(af[mf][1], bfr[nf][1], acc[h * 4 + mf][nf]);
        }
    }
  }

  const int er = lq * 4;
  const int seg = n0 >> 11;
  const int gc = (n0 & 2047) + wn * 64 + l15;
  #pragma unroll
  for (int mf = 0; mf < 8; mf++)
    #pragma unroll
    for (int nf = 0; nf < 4; nf++) {
      const int gr = m0 + wm * 128 + mf * 16 + er;
      #pragma unroll
      for (int jj = 0; jj < 4; jj++) {
        const size_t off2 = (size_t)(gr + jj) * 2048 + gc + nf * 16;
        const float v = acc[mf][nf][jj];
        if (seg == 0) {
          oq[off2] = (bf16_t)(1.0f / (1.0f + expf(-v)));
        } else if (seg == 1) {
          okk[off2] = (bf16_t)(1.0f / (1.0f + expf(v)));
          og[off2] = fminf(v, 0.0f) - log1pf(expf(-fabsf(v)));
        } else {
          ov[off2] = (bf16_t)v;
        }
      }
    }
}

// ---------------------------------------------------------------------------
// Wo GEMM: 128x128 tile, BK=64, m97 2-barrier loop (R9/R11-verified config).
// Linear n-fastest mapping (R10's remap tripled FETCH: do not reorder).
// f32 out with fused RMS row-scale; gnorm_w pre-folded into Wb.
// ---------------------------------------------------------------------------
__global__ __launch_bounds__(256, 2)
void gemm_bt2(const bf16_t* __restrict__ A, const bf16_t* __restrict__ Bw,
              float* __restrict__ of, const float* __restrict__ rsc,
              int M, int N, int K)
{
  __shared__ __align__(16) bf16_t As[128 * 64];
  __shared__ __align__(16) bf16_t Bs[128 * 64];
  const int tt   = threadIdx.x;
  const int wave = tt >> 6;
  const int lane = tt & 63;
  const int nbn = N >> 7;
  const int m0 = (int)(blockIdx.x / nbn) << 7;
  const int n0 = (int)(blockIdx.x % nbn) << 7;
  const int wr = (wave >> 1) * 64;
  const int wc = (wave & 1) * 64;
  const int l15 = lane & 15, lq = lane >> 4;

  const int tk0 = (lq * 16) ^ ((lane & 7) << 4);
  const int tk1 = (64 + lq * 16) ^ ((lane & 7) << 4);

  const int srow = wave * 8 + (lane >> 3);
  const int sg = (lane & 7) ^ (lane >> 3);
  const bf16_t* pA = A  + (size_t)(m0 + srow) * K + sg * 8;
  const bf16_t* pB = Bw + (size_t)(n0 + srow) * K + sg * 8;

  f32x4 acc[4][4] = {};

  for (int kt = 0; kt < K; kt += 64) {
    #pragma unroll
    for (int i = 0; i < 4; i++) {
      gl2lds16(pA + (size_t)i * 32 * K + kt, (void*)(As + wave * 512 + i * 2048));
      gl2lds16(pB + (size_t)i * 32 * K + kt, (void*)(Bs + wave * 512 + i * 2048));
    }
    asm volatile("s_waitcnt vmcnt(0)" ::: "memory");
    __syncthreads();

    bf16x8 a[2][4], b[2][4];
    #pragma unroll
    for (int mf = 0; mf < 4; mf++) {
      const char* rp = (const char*)As + (wr + mf * 16 + l15) * 128;
      a[0][mf] = *(const bf16x8*)(rp + tk0);
      a[1][mf] = *(const bf16x8*)(rp + tk1);
    }
    #pragma unroll
    for (int nf = 0; nf < 4; nf++) {
      const char* rp = (const char*)Bs + (wc + nf * 16 + l15) * 128;
      b[0][nf] = *(const bf16x8*)(rp + tk0);
      b[1][nf] = *(const bf16x8*)(rp + tk1);
    }
    #pragma unroll
    for (int kh = 0; kh < 2; kh++)
      #pragma unroll
      for (int mf = 0; mf < 4; mf++)
        #pragma unroll
        for (int nf = 0; nf < 4; nf++)
          acc[mf][nf] = MFMA16(a[kh][mf], b[kh][nf], acc[mf][nf]);
    __syncthreads();
  }

  const int er = lq * 4;
  const int gc = n0 + wc + l15;
  #pragma unroll
  for (int mf = 0; mf < 4; mf++) {
    const int gr = m0 + wr + mf * 16 + er;
    #pragma unroll
    for (int jj = 0; jj < 4; jj++) {
      const float s = rsc[gr + jj];
      #pragma unroll
      for (int nf = 0; nf < 4; nf++)
        of[(size_t)(gr + jj) * N + gc + nf * 16] = acc[mf][nf][jj] * s;
    }
  }
}

// ---------------------------------------------------------------------------
__global__ void f2b_kernel(const float* __restrict__ in, bf16_t* __restrict__ out, int n8)
{
  const int idx = blockIdx.x * 256 + threadIdx.x;
  if (idx >= n8) return;
  const float4 a = *(const float4*)(in + (size_t)idx * 8);
  const float4 b = *(const float4*)(in + (size_t)idx * 8 + 4);
  bf16x8 o;
  o[0] = (bf16_t)a.x; o[1] = (bf16_t)a.y; o[2] = (bf16_t)a.z; o[3] = (bf16_t)a.w;
  o[4] = (bf16_t)b.x; o[5] = (bf16_t)b.y; o[6] = (bf16_t)b.z; o[7] = (bf16_t)b.w;
  *(bf16x8*)(out + (size_t)idx * 8) = o;
}

// 3 weight matrices (Wq,Wf,Wi) -> one contiguous bf16 buffer, one launch
__global__ void f2b3_kernel(const float* __restrict__ w0, const float* __restrict__ w1,
                            const float* __restrict__ w2, bf16_t* __restrict__ out, int n8)
{
  const int idx = blockIdx.x * 256 + threadIdx.x;
  if (idx >= 3 * n8) return;
  const int which = idx / n8, j = idx - which * n8;
  const float* src = (which == 0) ? w0 : (which == 1) ? w1 : w2;
  const float4 a = *(const float4*)(src + (size_t)j * 8);
  const float4 b = *(const float4*)(src + (size_t)j * 8 + 4);
  bf16x8 o;
  o[0] = (bf16_t)a.x; o[1] = (bf16_t)a.y; o[2] = (bf16_t)a.z; o[3] = (bf16_t)a.w;
  o[4] = (bf16_t)b.x; o[5] = (bf16_t)b.y; o[6] = (bf16_t)b.z; o[7] = (bf16_t)b.w;
  *(bf16x8*)(out + (size_t)idx * 8) = o;
}

// Wo convert with gnorm_w folded: Wb[n][k] = bf16(Wo[n][k] * gw[k])
__global__ void f2bw_kernel(const float* __restrict__ in, const float* __restrict__ gw,
                            bf16_t* __restrict__ out, int n8)
{
  const int idx = blockIdx.x * 256 + threadIdx.x;
  if (idx >= n8) return;
  const int k0 = (idx * 8) & 2047;
  const float4 a = *(const float4*)(in + (size_t)idx * 8);
  const float4 b = *(const float4*)(in + (size_t)idx * 8 + 4);
  const float4 g0 = *(const float4*)(gw + k0);
  const float4 g1 = *(const float4*)(gw + k0 + 4);
  bf16x8 o;
  o[0] = (bf16_t)(a.x * g0.x); o[1] = (bf16_t)(a.y * g0.y);
  o[2] = (bf16_t)(a.z * g0.z); o[3] = (bf16_t)(a.w * g0.w);
  o[4] = (bf16_t)(b.x * g1.x); o[5] = (bf16_t)(b.y * g1.y);
  o[6] = (bf16_t)(b.z * g1.z); o[7] = (bf16_t)(b.w * g1.w);
  *(bf16x8*)(out + (size_t)idx * 8) = o;
}

// ---------------------------------------------------------------------------
// prep2: per (b,h,c): gc = cumsum(g); IN-PLACE q <- q*e^(gc-gl/2),
// k <- k*e^(gl/2-gc); eglh[blk][d] = e^(gl_d/2).  (mid-point gauge)
// ---------------------------------------------------------------------------
__global__ __launch_bounds__(256)
void prep2_kernel(bf16_t* __restrict__ qb, bf16_t* __restrict__ kb,
                  const float* __restrict__ g32, float* __restrict__ eglh)
{
  __shared__ __align__(16) float gs[64][132];
  __shared__ float gls[128];
  const int blk = blockIdx.x;
  const int c = blk & 31, h = (blk >> 5) & 15, b = blk >> 9;
  const size_t row0 = (size_t)b * 2048 + (size_t)c * 64;
  const int col0 = h * 128;
  const int tt = threadIdx.x;

  #pragma unroll
  for (int s = 0; s < 8; s++) {
    const int u = tt + s * 256;
    const int t = u >> 5, d4 = (u & 31) * 4;
    *(float4*)&gs[t][d4] = *(const float4*)(g32 + (row0 + t) * 2048 + col0 + d4);
  }
  __syncthreads();
  if (tt < 128) {
    float run = 0.0f;
    for (int t = 0; t < 64; t++) { run += gs[t][tt]; gs[t][tt] = run; }
    gls[tt] = 0.5f * run;
    eglh[(size_t)blk * 128 + tt] = expf(0.5f * run);
  }
  __syncthreads();
  #pragma unroll
  for (int s = 0; s < 4; s++) {
    const int u = tt + s * 256;
    const int t = u >> 4, d8 = (u & 15) * 8;
    bf16_t* qp = qb + (row0 + t) * 2048 + col0 + d8;
    bf16_t* kp = kb + (row0 + t) * 2048 + col0 + d8;
    const bf16x8 q8 = *(const bf16x8*)qp;
    const bf16x8 k8 = *(const bf16x8*)kp;
    bf16x8 qo, ko2;
    #pragma unroll
    for (int j = 0; j < 8; j++) {
      const float gc = gs[t][d8 + j];
      const float gh = gls[d8 + j];
      qo[j]  = (bf16_t)((float)q8[j] * expf(gc - gh));
      ko2[j] = (bf16_t)((float)k8[j] * expf(gh - gc));
    }
    *(bf16x8*)qp = qo;
    *(bf16x8*)kp = ko2;
  }
}

// ---------------------------------------------------------------------------
// state2: per (bh, e-half, d-half): sequential 32-chunk recurrence on a
// 64x64 quarter of T = S^T. Stores pre-update state scaled by e^(gl_c/2).
// ---------------------------------------------------------------------------
__global__ __launch_bounds__(256)
void state2_kernel(const bf16_t* __restrict__ kb, const bf16_t* __restrict__ vb,
                   const float* __restrict__ eglh, bf16_t* __restrict__ ST)
{
  __shared__ __align__(16) bf16_t kgt[64][72];
  __shared__ __align__(16) bf16_t vt[64][72];
  __shared__ float ehs[64];
  const int blk = blockIdx.x;                   // bh*4 + eh*2 + dh
  const int dh = blk & 1, eh = (blk >> 1) & 1, bh = blk >> 2;
  const int b = bh >> 4, h = bh & 15;
  const int col0 = h * 128;
  const int tt = threadIdx.x, wave = tt >> 6, lane = tt & 63;
  const int r = lane & 15, ko = (lane >> 4) * 8;
  const int d0 = dh * 64, e0 = eh * 64;
  f32x4 acc[4] = {};

  for (int c = 0; c < 32; c++) {
    const size_t cb = (size_t)bh * 32 + c;
    const size_t row0 = (size_t)b * 2048 + (size_t)c * 64;
    if (tt < 64) ehs[tt] = eglh[cb * 128 + d0 + tt];
    __syncthreads();
    #pragma unroll
    for (int s = 0; s < 2; s++) {
      const int u = tt + s * 256;
      const int t = u >> 3, d8 = (u & 7) * 8;
      const bf16x8 kv = *(const bf16x8*)(kb + (row0 + t) * 2048 + col0 + d0 + d8);
      const bf16x8 vv = *(const bf16x8*)(vb + (row0 + t) * 2048 + col0 + e0 + d8);
      #pragma unroll
      for (int j = 0; j < 8; j++) {
        kgt[d8 + j][t] = (bf16_t)((float)kv[j] * ehs[d8 + j]);
        vt[d8 + j][t]  = vv[j];
      }
    }
    __syncthreads();
    #pragma unroll
    for (int nf = 0; nf < 4; nf++) {
      const int d = nf * 16 + r;
      const float sd = ehs[d];
      #pragma unroll
      for (int jj = 0; jj < 4; jj++) {
        const int e = e0 + wave * 16 + (lane >> 4) * 4 + jj;
        ST[(cb * 128 + e) * 128 + d0 + d] = (bf16_t)(acc[nf][jj] * sd);
      }
    }
    #pragma unroll
    for (int nf = 0; nf < 4; nf++) {
      const float ev = ehs[nf * 16 + r];
      const float e2 = ev * ev;
      #pragma unroll
      for (int jj = 0; jj < 4; jj++) acc[nf][jj] *= e2;
    }
    #pragma unroll
    for (int ks = 0; ks < 2; ks++) {
      const bf16x8 a = *(const bf16x8*)&vt[wave * 16 + r][ks * 32 + ko];
      #pragma unroll
      for (int nf = 0; nf < 4; nf++) {
        const bf16x8 bfr = *(const bf16x8*)&kgt[nf * 16 + r][ks * 32 + ko];
        acc[nf] = MFMA16(a, bfr, acc[nf]);
      }
    }
    __syncthreads();
  }
}

// ---------------------------------------------------------------------------
// chunk2: per (b,h,c): A = qg2 @ kd2^T (tril) -> P ; o = P@v + qg2@ST'
// ---------------------------------------------------------------------------
__global__ __launch_bounds__(256)
void chunk2_kernel(const bf16_t* __restrict__ qb, const bf16_t* __restrict__ kb,
                   const bf16_t* __restrict__ vb, const bf16_t* __restrict__ ST,
                   bf16_t* __restrict__ o16)
{
  __shared__ __align__(16) bf16_t qgs[64][136];
  __shared__ __align__(16) bf16_t kds[64][136];
  __shared__ __align__(16) bf16_t vTs[128][72];
  __shared__ __align__(16) bf16_t Ps[64][72];
  const int blk = blockIdx.x;
  const int c = blk & 31, h = (blk >> 5) & 15, b = blk >> 9;
  const size_t row0 = (size_t)b * 2048 + (size_t)c * 64;
  const int col0 = h * 128;
  const int tt = threadIdx.x, wave = tt >> 6, lane = tt & 63;
  const int r = lane & 15, ko = (lane >> 4) * 8;

  #pragma unroll
  for (int s = 0; s < 4; s++) {
    const int u = tt + s * 256;
    const int t = u >> 4, d8 = (u & 15) * 8;
    *(bf16x8*)&qgs[t][d8] = *(const bf16x8*)(qb + (row0 + t) * 2048 + col0 + d8);
    *(bf16x8*)&kds[t][d8] = *(const bf16x8*)(kb + (row0 + t) * 2048 + col0 + d8);
  }
  #pragma unroll
  for (int s = 0; s < 4; s++) {
    const int u = tt + s * 256;
    const int t = u >> 4, e8 = (u & 15) * 8;
    const bf16x8 vv = *(const bf16x8*)(vb + (row0 + t) * 2048 + col0 + e8);
    #pragma unroll
    for (int j = 0; j < 8; j++) vTs[e8 + j][t] = vv[j];
  }
  __syncthreads();

  bf16x8 aq[4];
  #pragma unroll
  for (int ks = 0; ks < 4; ks++) aq[ks] = *(const bf16x8*)&qgs[wave * 16 + r][ks * 32 + ko];

  f32x4 accA[4] = {};
  #pragma unroll
  for (int ks = 0; ks < 4; ks++)
    #pragma unroll
    for (int sf = 0; sf < 4; sf++) {
      const bf16x8 bfr = *(const bf16x8*)&kds[sf * 16 + r][ks * 32 + ko];
      accA[sf] = MFMA16(aq[ks], bfr, accA[sf]);
    }

  #pragma unroll
  for (int sf = 0; sf < 4; sf++)
    #pragma unroll
    for (int jj = 0; jj < 4; jj++) {
      const int t = wave * 16 + (lane >> 4) * 4 + jj;
      const int s = sf * 16 + r;
      Ps[t][s] = (bf16_t)(t >= s ? accA[sf][jj] : 0.0f);
    }

  f32x4 acc[8] = {};
  const size_t stbase = (size_t)blk * 128 * 128;
  #pragma unroll
  for (int ks = 0; ks < 4; ks++)
    #pragma unroll
    for (int ne = 0; ne < 8; ne++) {
      const bf16x8 bfr = *(const bf16x8*)(ST + stbase + (size_t)(ne * 16 + r) * 128 + ks * 32 + ko);
      acc[ne] = MFMA16(aq[ks], bfr, acc[ne]);
    }
  #pragma unroll
  for (int ks = 0; ks < 2; ks++) {
    const bf16x8 pa = *(const bf16x8*)&Ps[wave * 16 + r][ks * 32 + ko];
    #pragma unroll
    for (int ne = 0; ne < 8; ne++) {
      const bf16x8 bfr = *(const bf16x8*)&vTs[ne * 16 + r][ks * 32 + ko];
      acc[ne] = MFMA16(pa, bfr, acc[ne]);
    }
  }

  #pragma unroll
  for (int ne = 0; ne < 8; ne++)
    #pragma unroll
    for (int jj = 0; jj < 4; jj++) {
      const int t = wave * 16 + (lane >> 4) * 4 + jj;
      const int e = ne * 16 + r;
      o16[(row0 + t) * 2048 + col0 + e] = (bf16_t)acc[ne][jj];
    }
}

// ---------------------------------------------------------------------------
// RMS row-scale only: rsc[row] = rsqrt(mean(o16[row]^2) + eps)
// ---------------------------------------------------------------------------
__global__ __launch_bounds__(256)
void rmsr_kernel(const bf16_t* __restrict__ o16, float* __restrict__ rsc)
{
  __shared__ float red[4];
  const size_t row = blockIdx.x;
  const int tt = threadIdx.x;
  const bf16x8 v = *(const bf16x8*)(o16 + row * 2048 + tt * 8);
  float ss = 0.0f;
  #pragma unroll
  for (int j = 0; j < 8; j++) { const float f = (float)v[j]; ss += f * f; }
  #pragma unroll
  for (int off = 32; off > 0; off >>= 1) ss += __shfl_down(ss, off);
  if ((tt & 63) == 0) red[tt >> 6] = ss;
  __syncthreads();
  if (tt == 0)
    rsc[row] = rsqrtf((red[0] + red[1] + red[2] + red[3]) * (1.0f / 2048.0f) + 1e-5f);
}

// ---------------------------------------------------------------------------
extern "C" void kernel_launch(void* const* d_in, const int* in_sizes, int n_in,
                              void* d_out, int out_size, void* d_ws, size_t ws_size,
                              hipStream_t stream)
{
  const float* x  = (const float*)d_in[0];
  const float* Wq = (const float*)d_in[1];
  const float* Wf = (const float*)d_in[2];
  const float* Wi = (const float*)d_in[3];
  const float* Wo = (const float*)d_in[4];
  const float* gw = (const float*)d_in[5];
  float* out = (float*)d_out;
  char* ws = (char*)d_ws;

  const int K = 2048;
  const size_t MB = 1ull << 20;
  const int LDS = 131072;

  (void)hipFuncSetAttribute((const void*)gemm256s,
      hipFuncAttributeMaxDynamicSharedMemorySize, LDS);

  auto run = [&](const float* xs, float* outs, int nbs) {
    const int Ms = nbs * 2048;
    const size_t Sx = (size_t)Ms * 2048 * 2;     // bf16 matrix bytes
    bf16_t* xb  = (bf16_t*)(ws + 0);
    bf16_t* qb  = (bf16_t*)(ws + Sx);
    bf16_t* kb  = (bf16_t*)(ws + 2 * Sx);
    bf16_t* vb  = (bf16_t*)(ws + 3 * Sx);
    float*  g32 = (float*) (ws + 4 * Sx);        // 2*Sx bytes
    bf16_t* Wb  = (bf16_t*)(ws + 6 * Sx);        // 24 MiB (QKV fused / Wo)
    float*  egh = (float*) (ws + 6 * Sx + 24 * MB);
    float*  rsc = (float*) (ws + 6 * Sx + 25 * MB);
    bf16_t* STp = (bf16_t*)(ws + 4 * Sx);        // alias g32 (dead after prep)
    bf16_t* o16 = (bf16_t*)(ws + 0);             // alias xb  (dead after QKV gemm)

    const int n8x = Ms * 2048 / 8;
    const int n8w = 2048 * 2048 / 8;

    f2b_kernel<<<(n8x + 255) / 256, 256, 0, stream>>>(xs, xb, n8x);
    f2b3_kernel<<<(3 * n8w + 255) / 256, 256, 0, stream>>>(Wq, Wf, Wi, Wb, n8w);

    gemm256s<<<(Ms / 256) * (6144 / 256), 512, LDS, stream>>>(
        xb, Wb, qb, kb, vb, g32, Ms, 6144, K);

    prep2_kernel<<<nbs * 512, 256, 0, stream>>>(qb, kb, g32, egh);
    state2_kernel<<<nbs * 64, 256, 0, stream>>>(kb, vb, egh, STp);
    chunk2_kernel<<<nbs * 512, 256, 0, stream>>>(qb, kb, vb, STp, o16);
    rmsr_kernel<<<Ms, 256, 0, stream>>>(o16, rsc);

    f2bw_kernel<<<(n8w + 255) / 256, 256, 0, stream>>>(Wo, gw, Wb, n8w);
    gemm_bt2<<<(Ms / 128) * (2048 / 128), 256, 0, stream>>>(
        o16, Wb, outs, rsc, Ms, 2048, K);
  };

  const size_t Sx_full = (size_t)8192 * 2048 * 2;
  const size_t need_full = 6 * Sx_full + 26 * MB;
  if (ws_size >= need_full) {
    run(x, out, 4);
  } else {
    for (int sb = 0; sb < 4; sb++)
      run(x + (size_t)sb * 2048 * 2048, out + (size_t)sb * 2048 * 2048, 1);
  }

  (void)in_sizes; (void)n_in; (void)out_size;
}

// Round 13
// 588.984 us; speedup vs baseline: 1.4026x; 1.4026x over previous
//
#include <hip/hip_runtime.h>
#include <math.h>

typedef __bf16 bf16_t;
typedef __bf16 bf16x8 __attribute__((ext_vector_type(8)));
typedef float  f32x4  __attribute__((ext_vector_type(4)));

__device__ __forceinline__ void gl2lds16(const void* g, void* l) {
  __builtin_amdgcn_global_load_lds((__attribute__((address_space(1))) void*)g,
                                   (__attribute__((address_space(3))) void*)l,
                                   16, 0, 0);
}

#define MFMA16(a, b, c) __builtin_amdgcn_mfma_f32_16x16x32_bf16(a, b, c, 0, 0, 0)

// ---------------------------------------------------------------------------
// 128x128 tile, BK=64, 4 waves, 32 KiB LDS single-buffer, m97 2-barrier loop.
// R9/R11-verified config: 597 TF fused QKV = ~93% of this structure's LDS-BW
// ceiling (0.095 B/MAC at ~100 B/cy/CU). High-occupancy (~3 blocks/CU) TLP
// regime. Block mapping: LINEAR n-fastest -- R10's XCD remap tripled FETCH.
// 256'-tile alternatives tried 6x (R4-R8, R12): all worse (1 block/CU kills
// TLP; plain-HIP pipeline cannot replace it). This is the plateau structure.
// T2 swizzle, 128B rows: granule slot = (khalf*4+lq) ^ (lane&7); staging
// pre-swizzles the GLOBAL source column (LDS dest linear, m104 rule).
// C = A * B^T. MODE 0: fused QKV epilogue (seg = n0>>11: 0->q=sigmoid,
// 1->k=sigmoid(-v) + g=logsigmoid(v), 2->v).
// MODE 1: f32 out with fused RMS row-scale: out[r,c] = rsc[r] * (A Wb^T)[r,c]
// (gnorm_w pre-folded into Wb).
// ---------------------------------------------------------------------------
template<int MODE>
__global__ __launch_bounds__(256, 2)
void gemm_bt2(const bf16_t* __restrict__ A, const bf16_t* __restrict__ Bw,
              bf16_t* __restrict__ oq, bf16_t* __restrict__ okk,
              bf16_t* __restrict__ ov, float* __restrict__ og,
              float* __restrict__ of, const float* __restrict__ rsc,
              int M, int N, int K)
{
  __shared__ __align__(16) bf16_t As[128 * 64];
  __shared__ __align__(16) bf16_t Bs[128 * 64];
  const int tt   = threadIdx.x;
  const int wave = tt >> 6;
  const int lane = tt & 63;
  const int nbn = N >> 7;
  const int m0 = (int)(blockIdx.x / nbn) << 7;
  const int n0 = (int)(blockIdx.x % nbn) << 7;
  const int wr = (wave >> 1) * 64;
  const int wc = (wave & 1) * 64;
  const int l15 = lane & 15, lq = lane >> 4;

  // read-side swizzled column byte offsets within a 128B row (k-halves 0/1)
  const int tk0 = (lq * 16) ^ ((lane & 7) << 4);
  const int tk1 = (64 + lq * 16) ^ ((lane & 7) << 4);

  // staging: wave base w*1024B (+i*4096B); lane covers row w*8+i*32+(l>>3),
  // LDS slot l&7 -> pre-swizzled global granule (l&7)^(l>>3)
  const int srow = wave * 8 + (lane >> 3);
  const int sg = (lane & 7) ^ (lane >> 3);
  const bf16_t* pA = A  + (size_t)(m0 + srow) * K + sg * 8;
  const bf16_t* pB = Bw + (size_t)(n0 + srow) * K + sg * 8;

  f32x4 acc[4][4] = {};

  for (int kt = 0; kt < K; kt += 64) {
    #pragma unroll
    for (int i = 0; i < 4; i++) {
      gl2lds16(pA + (size_t)i * 32 * K + kt, (void*)(As + wave * 512 + i * 2048));
      gl2lds16(pB + (size_t)i * 32 * K + kt, (void*)(Bs + wave * 512 + i * 2048));
    }
    asm volatile("s_waitcnt vmcnt(0)" ::: "memory");
    __syncthreads();

    bf16x8 a[2][4], b[2][4];
    #pragma unroll
    for (int mf = 0; mf < 4; mf++) {
      const char* rp = (const char*)As + (wr + mf * 16 + l15) * 128;
      a[0][mf] = *(const bf16x8*)(rp + tk0);
      a[1][mf] = *(const bf16x8*)(rp + tk1);
    }
    #pragma unroll
    for (int nf = 0; nf < 4; nf++) {
      const char* rp = (const char*)Bs + (wc + nf * 16 + l15) * 128;
      b[0][nf] = *(const bf16x8*)(rp + tk0);
      b[1][nf] = *(const bf16x8*)(rp + tk1);
    }
    #pragma unroll
    for (int kh = 0; kh < 2; kh++)
      #pragma unroll
      for (int mf = 0; mf < 4; mf++)
        #pragma unroll
        for (int nf = 0; nf < 4; nf++)
          acc[mf][nf] = MFMA16(a[kh][mf], b[kh][nf], acc[mf][nf]);
    __syncthreads();
  }

  const int er = lq * 4;
  if (MODE == 0) {
    const int seg = n0 >> 11;
    const int gc = (n0 & 2047) + wc;
    #pragma unroll
    for (int mf = 0; mf < 4; mf++)
      #pragma unroll
      for (int nf = 0; nf < 4; nf++) {
        const int gr = m0 + wr + mf * 16 + er;
        #pragma unroll
        for (int jj = 0; jj < 4; jj++) {
          const size_t off2 = (size_t)(gr + jj) * 2048 + gc + nf * 16 + l15;
          const float v = acc[mf][nf][jj];
          if (seg == 0) {
            oq[off2] = (bf16_t)(1.0f / (1.0f + expf(-v)));
          } else if (seg == 1) {
            okk[off2] = (bf16_t)(1.0f / (1.0f + expf(v)));
            og[off2] = fminf(v, 0.0f) - log1pf(expf(-fabsf(v)));
          } else {
            ov[off2] = (bf16_t)v;
          }
        }
      }
  } else {
    const int gc = n0 + wc + l15;
    #pragma unroll
    for (int mf = 0; mf < 4; mf++) {
      const int gr = m0 + wr + mf * 16 + er;
      #pragma unroll
      for (int jj = 0; jj < 4; jj++) {
        const float s = rsc[gr + jj];
        #pragma unroll
        for (int nf = 0; nf < 4; nf++)
          of[(size_t)(gr + jj) * N + gc + nf * 16] = acc[mf][nf][jj] * s;
      }
    }
  }
}

// ---------------------------------------------------------------------------
__global__ void f2b_kernel(const float* __restrict__ in, bf16_t* __restrict__ out, int n8)
{
  const int idx = blockIdx.x * 256 + threadIdx.x;
  if (idx >= n8) return;
  const float4 a = *(const float4*)(in + (size_t)idx * 8);
  const float4 b = *(const float4*)(in + (size_t)idx * 8 + 4);
  bf16x8 o;
  o[0] = (bf16_t)a.x; o[1] = (bf16_t)a.y; o[2] = (bf16_t)a.z; o[3] = (bf16_t)a.w;
  o[4] = (bf16_t)b.x; o[5] = (bf16_t)b.y; o[6] = (bf16_t)b.z; o[7] = (bf16_t)b.w;
  *(bf16x8*)(out + (size_t)idx * 8) = o;
}

// 3 weight matrices (Wq,Wf,Wi) -> one contiguous bf16 buffer, one launch
__global__ void f2b3_kernel(const float* __restrict__ w0, const float* __restrict__ w1,
                            const float* __restrict__ w2, bf16_t* __restrict__ out, int n8)
{
  const int idx = blockIdx.x * 256 + threadIdx.x;
  if (idx >= 3 * n8) return;
  const int which = idx / n8, j = idx - which * n8;
  const float* src = (which == 0) ? w0 : (which == 1) ? w1 : w2;
  const float4 a = *(const float4*)(src + (size_t)j * 8);
  const float4 b = *(const float4*)(src + (size_t)j * 8 + 4);
  bf16x8 o;
  o[0] = (bf16_t)a.x; o[1] = (bf16_t)a.y; o[2] = (bf16_t)a.z; o[3] = (bf16_t)a.w;
  o[4] = (bf16_t)b.x; o[5] = (bf16_t)b.y; o[6] = (bf16_t)b.z; o[7] = (bf16_t)b.w;
  *(bf16x8*)(out + (size_t)idx * 8) = o;
}

// Wo convert with gnorm_w folded: Wb[n][k] = bf16(Wo[n][k] * gw[k])
__global__ void f2bw_kernel(const float* __restrict__ in, const float* __restrict__ gw,
                            bf16_t* __restrict__ out, int n8)
{
  const int idx = blockIdx.x * 256 + threadIdx.x;
  if (idx >= n8) return;
  const int k0 = (idx * 8) & 2047;
  const float4 a = *(const float4*)(in + (size_t)idx * 8);
  const float4 b = *(const float4*)(in + (size_t)idx * 8 + 4);
  const float4 g0 = *(const float4*)(gw + k0);
  const float4 g1 = *(const float4*)(gw + k0 + 4);
  bf16x8 o;
  o[0] = (bf16_t)(a.x * g0.x); o[1] = (bf16_t)(a.y * g0.y);
  o[2] = (bf16_t)(a.z * g0.z); o[3] = (bf16_t)(a.w * g0.w);
  o[4] = (bf16_t)(b.x * g1.x); o[5] = (bf16_t)(b.y * g1.y);
  o[6] = (bf16_t)(b.z * g1.z); o[7] = (bf16_t)(b.w * g1.w);
  *(bf16x8*)(out + (size_t)idx * 8) = o;
}

// ---------------------------------------------------------------------------
// prep2: per (b,h,c): gc = cumsum(g); IN-PLACE q <- q*e^(gc-gl/2),
// k <- k*e^(gl/2-gc); eglh[blk][d] = e^(gl_d/2).  (mid-point gauge)
// ---------------------------------------------------------------------------
__global__ __launch_bounds__(256)
void prep2_kernel(bf16_t* __restrict__ qb, bf16_t* __restrict__ kb,
                  const float* __restrict__ g32, float* __restrict__ eglh)
{
  __shared__ __align__(16) float gs[64][132];
  __shared__ float gls[128];
  const int blk = blockIdx.x;
  const int c = blk & 31, h = (blk >> 5) & 15, b = blk >> 9;
  const size_t row0 = (size_t)b * 2048 + (size_t)c * 64;
  const int col0 = h * 128;
  const int tt = threadIdx.x;

  #pragma unroll
  for (int s = 0; s < 8; s++) {
    const int u = tt + s * 256;
    const int t = u >> 5, d4 = (u & 31) * 4;
    *(float4*)&gs[t][d4] = *(const float4*)(g32 + (row0 + t) * 2048 + col0 + d4);
  }
  __syncthreads();
  if (tt < 128) {
    float run = 0.0f;
    for (int t = 0; t < 64; t++) { run += gs[t][tt]; gs[t][tt] = run; }
    gls[tt] = 0.5f * run;
    eglh[(size_t)blk * 128 + tt] = expf(0.5f * run);
  }
  __syncthreads();
  #pragma unroll
  for (int s = 0; s < 4; s++) {
    const int u = tt + s * 256;
    const int t = u >> 4, d8 = (u & 15) * 8;
    bf16_t* qp = qb + (row0 + t) * 2048 + col0 + d8;
    bf16_t* kp = kb + (row0 + t) * 2048 + col0 + d8;
    const bf16x8 q8 = *(const bf16x8*)qp;
    const bf16x8 k8 = *(const bf16x8*)kp;
    bf16x8 qo, ko2;
    #pragma unroll
    for (int j = 0; j < 8; j++) {
      const float gc = gs[t][d8 + j];
      const float gh = gls[d8 + j];
      qo[j]  = (bf16_t)((float)q8[j] * expf(gc - gh));
      ko2[j] = (bf16_t)((float)k8[j] * expf(gh - gc));
    }
    *(bf16x8*)qp = qo;
    *(bf16x8*)kp = ko2;
  }
}

// ---------------------------------------------------------------------------
// state2: per (bh, e-half, d-half): sequential 32-chunk recurrence on a
// 64x64 quarter of T = S^T. Stores pre-update state scaled by e^(gl_c/2).
// ---------------------------------------------------------------------------
__global__ __launch_bounds__(256)
void state2_kernel(const bf16_t* __restrict__ kb, const bf16_t* __restrict__ vb,
                   const float* __restrict__ eglh, bf16_t* __restrict__ ST)
{
  __shared__ __align__(16) bf16_t kgt[64][72];
  __shared__ __align__(16) bf16_t vt[64][72];
  __shared__ float ehs[64];
  const int blk = blockIdx.x;                   // bh*4 + eh*2 + dh
  const int dh = blk & 1, eh = (blk >> 1) & 1, bh = blk >> 2;
  const int b = bh >> 4, h = bh & 15;
  const int col0 = h * 128;
  const int tt = threadIdx.x, wave = tt >> 6, lane = tt & 63;
  const int r = lane & 15, ko = (lane >> 4) * 8;
  const int d0 = dh * 64, e0 = eh * 64;
  f32x4 acc[4] = {};

  for (int c = 0; c < 32; c++) {
    const size_t cb = (size_t)bh * 32 + c;
    const size_t row0 = (size_t)b * 2048 + (size_t)c * 64;
    if (tt < 64) ehs[tt] = eglh[cb * 128 + d0 + tt];
    __syncthreads();
    #pragma unroll
    for (int s = 0; s < 2; s++) {
      const int u = tt + s * 256;
      const int t = u >> 3, d8 = (u & 7) * 8;
      const bf16x8 kv = *(const bf16x8*)(kb + (row0 + t) * 2048 + col0 + d0 + d8);
      const bf16x8 vv = *(const bf16x8*)(vb + (row0 + t) * 2048 + col0 + e0 + d8);
      #pragma unroll
      for (int j = 0; j < 8; j++) {
        kgt[d8 + j][t] = (bf16_t)((float)kv[j] * ehs[d8 + j]);
        vt[d8 + j][t]  = vv[j];
      }
    }
    __syncthreads();
    #pragma unroll
    for (int nf = 0; nf < 4; nf++) {
      const int d = nf * 16 + r;
      const float sd = ehs[d];
      #pragma unroll
      for (int jj = 0; jj < 4; jj++) {
        const int e = e0 + wave * 16 + (lane >> 4) * 4 + jj;
        ST[(cb * 128 + e) * 128 + d0 + d] = (bf16_t)(acc[nf][jj] * sd);
      }
    }
    #pragma unroll
    for (int nf = 0; nf < 4; nf++) {
      const float ev = ehs[nf * 16 + r];
      const float e2 = ev * ev;
      #pragma unroll
      for (int jj = 0; jj < 4; jj++) acc[nf][jj] *= e2;
    }
    #pragma unroll
    for (int ks = 0; ks < 2; ks++) {
      const bf16x8 a = *(const bf16x8*)&vt[wave * 16 + r][ks * 32 + ko];
      #pragma unroll
      for (int nf = 0; nf < 4; nf++) {
        const bf16x8 bfr = *(const bf16x8*)&kgt[nf * 16 + r][ks * 32 + ko];
        acc[nf] = MFMA16(a, bfr, acc[nf]);
      }
    }
    __syncthreads();
  }
}

// ---------------------------------------------------------------------------
// chunk2: per (b,h,c): A = qg2 @ kd2^T (tril) -> P ; o = P@v + qg2@ST'
// ---------------------------------------------------------------------------
__global__ __launch_bounds__(256)
void chunk2_kernel(const bf16_t* __restrict__ qb, const bf16_t* __restrict__ kb,
                   const bf16_t* __restrict__ vb, const bf16_t* __restrict__ ST,
                   bf16_t* __restrict__ o16)
{
  __shared__ __align__(16) bf16_t qgs[64][136];
  __shared__ __align__(16) bf16_t kds[64][136];
  __shared__ __align__(16) bf16_t vTs[128][72];
  __shared__ __align__(16) bf16_t Ps[64][72];
  const int blk = blockIdx.x;
  const int c = blk & 31, h = (blk >> 5) & 15, b = blk >> 9;
  const size_t row0 = (size_t)b * 2048 + (size_t)c * 64;
  const int col0 = h * 128;
  const int tt = threadIdx.x, wave = tt >> 6, lane = tt & 63;
  const int r = lane & 15, ko = (lane >> 4) * 8;

  #pragma unroll
  for (int s = 0; s < 4; s++) {
    const int u = tt + s * 256;
    const int t = u >> 4, d8 = (u & 15) * 8;
    *(bf16x8*)&qgs[t][d8] = *(const bf16x8*)(qb + (row0 + t) * 2048 + col0 + d8);
    *(bf16x8*)&kds[t][d8] = *(const bf16x8*)(kb + (row0 + t) * 2048 + col0 + d8);
  }
  #pragma unroll
  for (int s = 0; s < 4; s++) {
    const int u = tt + s * 256;
    const int t = u >> 4, e8 = (u & 15) * 8;
    const bf16x8 vv = *(const bf16x8*)(vb + (row0 + t) * 2048 + col0 + e8);
    #pragma unroll
    for (int j = 0; j < 8; j++) vTs[e8 + j][t] = vv[j];
  }
  __syncthreads();

  bf16x8 aq[4];
  #pragma unroll
  for (int ks = 0; ks < 4; ks++) aq[ks] = *(const bf16x8*)&qgs[wave * 16 + r][ks * 32 + ko];

  f32x4 accA[4] = {};
  #pragma unroll
  for (int ks = 0; ks < 4; ks++)
    #pragma unroll
    for (int sf = 0; sf < 4; sf++) {
      const bf16x8 bfr = *(const bf16x8*)&kds[sf * 16 + r][ks * 32 + ko];
      accA[sf] = MFMA16(aq[ks], bfr, accA[sf]);
    }

  #pragma unroll
  for (int sf = 0; sf < 4; sf++)
    #pragma unroll
    for (int jj = 0; jj < 4; jj++) {
      const int t = wave * 16 + (lane >> 4) * 4 + jj;
      const int s = sf * 16 + r;
      Ps[t][s] = (bf16_t)(t >= s ? accA[sf][jj] : 0.0f);
    }

  f32x4 acc[8] = {};
  const size_t stbase = (size_t)blk * 128 * 128;
  #pragma unroll
  for (int ks = 0; ks < 4; ks++)
    #pragma unroll
    for (int ne = 0; ne < 8; ne++) {
      const bf16x8 bfr = *(const bf16x8*)(ST + stbase + (size_t)(ne * 16 + r) * 128 + ks * 32 + ko);
      acc[ne] = MFMA16(aq[ks], bfr, acc[ne]);
    }
  #pragma unroll
  for (int ks = 0; ks < 2; ks++) {
    const bf16x8 pa = *(const bf16x8*)&Ps[wave * 16 + r][ks * 32 + ko];
    #pragma unroll
    for (int ne = 0; ne < 8; ne++) {
      const bf16x8 bfr = *(const bf16x8*)&vTs[ne * 16 + r][ks * 32 + ko];
      acc[ne] = MFMA16(pa, bfr, acc[ne]);
    }
  }

  #pragma unroll
  for (int ne = 0; ne < 8; ne++)
    #pragma unroll
    for (int jj = 0; jj < 4; jj++) {
      const int t = wave * 16 + (lane >> 4) * 4 + jj;
      const int e = ne * 16 + r;
      o16[(row0 + t) * 2048 + col0 + e] = (bf16_t)acc[ne][jj];
    }
}

// ---------------------------------------------------------------------------
// RMS row-scale only: rsc[row] = rsqrt(mean(o16[row]^2) + eps)
// (the multiply is fused into the Wo GEMM epilogue; gnorm_w folded into Wb)
// ---------------------------------------------------------------------------
__global__ __launch_bounds__(256)
void rmsr_kernel(const bf16_t* __restrict__ o16, float* __restrict__ rsc)
{
  __shared__ float red[4];
  const size_t row = blockIdx.x;
  const int tt = threadIdx.x;
  const bf16x8 v = *(const bf16x8*)(o16 + row * 2048 + tt * 8);
  float ss = 0.0f;
  #pragma unroll
  for (int j = 0; j < 8; j++) { const float f = (float)v[j]; ss += f * f; }
  #pragma unroll
  for (int off = 32; off > 0; off >>= 1) ss += __shfl_down(ss, off);
  if ((tt & 63) == 0) red[tt >> 6] = ss;
  __syncthreads();
  if (tt == 0)
    rsc[row] = rsqrtf((red[0] + red[1] + red[2] + red[3]) * (1.0f / 2048.0f) + 1e-5f);
}

// ---------------------------------------------------------------------------
extern "C" void kernel_launch(void* const* d_in, const int* in_sizes, int n_in,
                              void* d_out, int out_size, void* d_ws, size_t ws_size,
                              hipStream_t stream)
{
  const float* x  = (const float*)d_in[0];
  const float* Wq = (const float*)d_in[1];
  const float* Wf = (const float*)d_in[2];
  const float* Wi = (const float*)d_in[3];
  const float* Wo = (const float*)d_in[4];
  const float* gw = (const float*)d_in[5];
  float* out = (float*)d_out;
  char* ws = (char*)d_ws;

  const int K = 2048;
  const size_t MB = 1ull << 20;

  auto run = [&](const float* xs, float* outs, int nbs) {
    const int Ms = nbs * 2048;
    const size_t Sx = (size_t)Ms * 2048 * 2;     // bf16 matrix bytes
    bf16_t* xb  = (bf16_t*)(ws + 0);
    bf16_t* qb  = (bf16_t*)(ws + Sx);
    bf16_t* kb  = (bf16_t*)(ws + 2 * Sx);
    bf16_t* vb  = (bf16_t*)(ws + 3 * Sx);
    float*  g32 = (float*) (ws + 4 * Sx);        // 2*Sx bytes
    bf16_t* Wb  = (bf16_t*)(ws + 6 * Sx);        // 24 MiB (QKV fused / Wo)
    float*  egh = (float*) (ws + 6 * Sx + 24 * MB);
    float*  rsc = (float*) (ws + 6 * Sx + 25 * MB);
    bf16_t* STp = (bf16_t*)(ws + 4 * Sx);        // alias g32 (dead after prep)
    bf16_t* o16 = (bf16_t*)(ws + 0);             // alias xb  (dead after QKV gemm)

    const int n8x = Ms * 2048 / 8;
    const int n8w = 2048 * 2048 / 8;

    f2b_kernel<<<(n8x + 255) / 256, 256, 0, stream>>>(xs, xb, n8x);
    f2b3_kernel<<<(3 * n8w + 255) / 256, 256, 0, stream>>>(Wq, Wf, Wi, Wb, n8w);

    gemm_bt2<0><<<(Ms / 128) * (6144 / 128), 256, 0, stream>>>(
        xb, Wb, qb, kb, vb, g32, nullptr, nullptr, Ms, 6144, K);

    prep2_kernel<<<nbs * 512, 256, 0, stream>>>(qb, kb, g32, egh);
    state2_kernel<<<nbs * 64, 256, 0, stream>>>(kb, vb, egh, STp);
    chunk2_kernel<<<nbs * 512, 256, 0, stream>>>(qb, kb, vb, STp, o16);
    rmsr_kernel<<<Ms, 256, 0, stream>>>(o16, rsc);

    f2bw_kernel<<<(n8w + 255) / 256, 256, 0, stream>>>(Wo, gw, Wb, n8w);
    gemm_bt2<1><<<(Ms / 128) * (2048 / 128), 256, 0, stream>>>(
        o16, Wb, nullptr, nullptr, nullptr, nullptr, outs, rsc, Ms, 2048, K);
  };

  const size_t Sx_full = (size_t)8192 * 2048 * 2;
  const size_t need_full = 6 * Sx_full + 26 * MB;
  if (ws_size >= need_full) {
    run(x, out, 4);
  } else {
    for (int sb = 0; sb < 4; sb++)
      run(x + (size_t)sb * 2048 * 2048, out + (size_t)sb * 2048 * 2048, 1);
  }

  (void)in_sizes; (void)n_in; (void)out_size;
}